// Round 2
// baseline (3247.857 us; speedup 1.0000x reference)
//
#include <hip/hip_runtime.h>
#include <math.h>
#include <stdint.h>

#define T_STEPS 100
#define B_DIM 128
#define I_DIM 1024
#define H_DIM 4096
#define O_DIM 512
#define T_CHUNK 20
#define HS_RING 21
#define HS_SLOT ((size_t)8*128*512)   // f16 per t-slot (8 m16-tiles x 128 kc x 512)
#define OV_LAG 21                     // ov step t' rides on hv step t = t'+21
#define RING_S 40                     // OG partial ring: 40 t-slots x 4 K-planes
#define TAIL_START 80                 // ov steps >= 80 handled by ov_tail

typedef _Float16 f16x8 __attribute__((ext_vector_type(8)));
typedef _Float16 f16x4 __attribute__((ext_vector_type(4)));
typedef float    f32x4 __attribute__((ext_vector_type(4)));

#define AS1 __attribute__((address_space(1)))
#define AS3 __attribute__((address_space(3)))

// Async global->LDS, 16B/lane. LDS dest is wave-uniform base + lane*16,
// which exactly matches the 1KB fragment-block layout (64 lanes x 16B).
__device__ __forceinline__ void gload_lds16(const _Float16* g, _Float16* l){
  __builtin_amdgcn_global_load_lds(
      (const AS1 unsigned*)(uintptr_t)g,
      (AS3 unsigned*)(unsigned)(uintptr_t)l, 16, 0, 0);
}

__device__ __forceinline__ unsigned fmap(float f){
  unsigned u = __float_as_uint(f);
  return (u & 0x80000000u) ? ~u : (u | 0x80000000u);
}
__device__ __forceinline__ float funmap(unsigned m){
  unsigned u = (m & 0x80000000u) ? (m & 0x7FFFFFFFu) : ~m;
  return __uint_as_float(u);
}
__device__ __forceinline__ float vth_of(unsigned m){
  return 0.3f * tanhf(0.3f * funmap(m));
}

__global__ __launch_bounds__(256) void init_kernel(float* hv, float* ovs,
                                                   uint32_t* cnt32,
                                                   unsigned* hmaxA, unsigned* omaxA,
                                                   unsigned* gctr)
{
  int i = blockIdx.x * 256 + threadIdx.x;
  if (i < B_DIM*H_DIM) hv[i] = 0.f;
  if (i < B_DIM*O_DIM) ovs[i] = 0.f;
  if (i < B_DIM*O_DIM/4) cnt32[i] = 0u;
  if (i < 64) gctr[i] = 0u;       // [0]=ov_tail barrier, [32]=hv_chunk barrier
  if (i < 128){
    // slot0 = "max of zero state" -> 0 -> vth 0 -> spike(0>0)=0
    unsigned v = (i==0) ? 0x80000000u : fmap(-3.0e38f);
    hmaxA[i] = v; omaxA[i] = v;
  }
}

// spike_data [B][I][T] fp32 -> fragment-tiled f16 hi/lo of (x*2048), chunk of 20 t.
__global__ __launch_bounds__(256) void prep_x(const float* __restrict__ sp,
                                              _Float16* __restrict__ Ahi,
                                              _Float16* __restrict__ Alo, int t0)
{
  __shared__ float tile[32][16][10];
  const int b16 = blockIdx.x, kc = blockIdx.y, tz = blockIdx.z;
  for (int e = threadIdx.x; e < 5120; e += 256){
    int tt = e % 10, row = e / 10;
    int bb = row >> 5, ii = row & 31;
    tile[ii][bb][tt] =
      sp[((size_t)(b16*16+bb)*I_DIM + kc*32 + ii)*T_STEPS + t0 + tz*10 + tt];
  }
  __syncthreads();
  for (int u = threadIdx.x; u < 640; u += 256){
    int tl = u >> 6, l = u & 63, kg = l >> 4, r = l & 15;
    f16x8 hi, lo;
    #pragma unroll
    for (int e=0;e<8;e++){
      float x = tile[kg*8+e][r][tl] * 2048.f;
      _Float16 h = (_Float16)x;
      hi[e] = h;
      lo[e] = (_Float16)(x - (float)h);
    }
    int t_local = tz*10 + tl;
    size_t off = ((size_t)(t_local*8 + b16)*32 + kc)*512 + kg*128 + r*8;
    *(f16x8*)(Ahi + off) = hi;
    *(f16x8*)(Alo + off) = lo;
  }
}

// Wh [H][I] and Wo [O][H] fp32 -> FB-tiled f16 hi/lo of (w*256), one launch.
__global__ __launch_bounds__(256) void prep_weights(
    const float* __restrict__ Wh, const float* __restrict__ Wo,
    _Float16* __restrict__ WHhi, _Float16* __restrict__ WHlo,
    _Float16* __restrict__ WOhi, _Float16* __restrict__ WOlo)
{
  const int blk = blockIdx.x;
  if (blk < 256){
    const int n16 = blk;
    for (int u = threadIdx.x; u < 2048; u += 256){
      int kc = u >> 6, l = u & 63, kg = l >> 4, r = l & 15;
      const float* src = Wh + (size_t)(n16*16 + r)*I_DIM + kc*32 + kg*8;
      f16x8 hi, lo;
      #pragma unroll
      for (int e=0;e<8;e++){
        float x = src[e] * 256.f;
        _Float16 h = (_Float16)x;
        hi[e] = h; lo[e] = (_Float16)(x - (float)h);
      }
      size_t off = ((size_t)n16*32 + kc)*512 + kg*128 + r*8;
      *(f16x8*)(WHhi + off) = hi;
      *(f16x8*)(WHlo + off) = lo;
    }
  } else {
    const int n16 = blk - 256;
    for (int u = threadIdx.x; u < 8192; u += 256){
      int kc = u >> 6, l = u & 63, kg = l >> 4, r = l & 15;
      const float* src = Wo + (size_t)(n16*16 + r)*H_DIM + kc*32 + kg*8;
      f16x8 hi, lo;
      #pragma unroll
      for (int e=0;e<8;e++){
        float x = src[e] * 256.f;
        _Float16 h = (_Float16)x;
        hi[e] = h; lo[e] = (_Float16)(x - (float)h);
      }
      size_t off = ((size_t)(n16*128 + kc))*512 + kg*128 + r*8;
      *(f16x8*)(WOhi + off) = hi;
      *(f16x8*)(WOlo + off) = lo;
    }
  }
}

// Batched GEMM1 (chunk of 20 t): G = XT @ Wh^T via fp16x3 exact-split MFMA.
// K-loop: async global_load_lds double-buffer, ONE barrier per kc (m97 form).
__global__ __launch_bounds__(256, 2) void gemm1_mfma(
    const _Float16* __restrict__ Ahi, const _Float16* __restrict__ Alo,
    const _Float16* __restrict__ Bhi, const _Float16* __restrict__ Blo,
    float* __restrict__ G)
{
  __shared__ __align__(16) _Float16 lds[2][4][8][512];   // 64 KB, 2 blocks/CU
  const int tid = threadIdx.x, wave = tid>>6, lane = tid&63;
  const int bn = blockIdx.x, bm = blockIdx.y;
  const int wm = wave>>1, wn = wave&1;

  const _Float16* srcbase = (wave==0)?Ahi:(wave==1)?Alo:(wave==2)?Bhi:Blo;
  const int r16b = ((wave<2) ? bm : bn)*8;
  const _Float16* gsrc = srcbase + (size_t)r16b*32*512 + lane*8;

  f32x4 acc[16];
  #pragma unroll
  for (int i=0;i<16;i++) acc[i] = (f32x4){0.f,0.f,0.f,0.f};

  #pragma unroll
  for (int q=0;q<8;q++)
    gload_lds16(gsrc + (size_t)q*32*512, &lds[0][wave][q][0]);

  for (int kc=0;kc<32;kc++){
    __syncthreads();
    if (kc < 31){
      #pragma unroll
      for (int q=0;q<8;q++)
        gload_lds16(gsrc + ((size_t)q*32 + kc+1)*512, &lds[(kc+1)&1][wave][q][0]);
    }
    const int cb = kc&1;
    f16x8 fAh[4], fAl[4], fBh[4], fBl[4];
    #pragma unroll
    for (int i=0;i<4;i++){
      fAh[i] = *(const f16x8*)&lds[cb][0][wm*4+i][lane*8];
      fAl[i] = *(const f16x8*)&lds[cb][1][wm*4+i][lane*8];
      fBh[i] = *(const f16x8*)&lds[cb][2][wn*4+i][lane*8];
      fBl[i] = *(const f16x8*)&lds[cb][3][wn*4+i][lane*8];
    }
    #pragma unroll
    for (int i=0;i<4;i++)
      #pragma unroll
      for (int j=0;j<4;j++)
        acc[i*4+j] = __builtin_amdgcn_mfma_f32_16x16x32_f16(fAh[i], fBh[j], acc[i*4+j], 0,0,0);
    #pragma unroll
    for (int i=0;i<4;i++)
      #pragma unroll
      for (int j=0;j<4;j++)
        acc[i*4+j] = __builtin_amdgcn_mfma_f32_16x16x32_f16(fAh[i], fBl[j], acc[i*4+j], 0,0,0);
    #pragma unroll
    for (int i=0;i<4;i++)
      #pragma unroll
      for (int j=0;j<4;j++)
        acc[i*4+j] = __builtin_amdgcn_mfma_f32_16x16x32_f16(fAl[i], fBh[j], acc[i*4+j], 0,0,0);
  }
  const int colw = lane&15, quad = lane>>4;
  const float sc = 1.f/(2048.f*256.f);
  float* eds = (float*)lds + wave*2048;
  __syncthreads();
  #pragma unroll
  for (int ih=0; ih<2; ih++){
    #pragma unroll
    for (int il=0; il<2; il++){
      int i = ih*2+il;
      #pragma unroll
      for (int j=0;j<4;j++)
        #pragma unroll
        for (int r=0;r<4;r++)
          eds[(il*16 + quad*4 + r)*64 + j*16 + colw] = acc[i*4+j][r]*sc;
    }
    #pragma unroll
    for (int rr8=0; rr8<8; rr8++){
      int row = rr8*4 + quad;
      float4 v = *(float4*)&eds[row*64 + colw*4];
      int m = bm*128 + wm*64 + ih*32 + row;
      int n = bn*128 + wn*64 + colw*4;
      *(float4*)&G[(size_t)m*H_DIM + n] = v;
    }
  }
}

// Per-chunk FIRST step only (t = 20c), 528 blocks:
//  blocks [0,512):  hv step t — emit hs_{t-1}, hv update, block max -> hmaxA[t+1]
//  blocks [512,528): ov step ovt = t-21 rider (same as before).
__global__ __launch_bounds__(256) void hv_step(
    const float* __restrict__ Gs, float* __restrict__ hv,
    _Float16* __restrict__ hs_slot,
    const unsigned* __restrict__ hmax_t, unsigned* __restrict__ hmax_n, int t,
    const float* __restrict__ OGp, float* __restrict__ ovs,
    uchar4* __restrict__ cnt8, unsigned* __restrict__ omaxA, int ovt)
{
  __shared__ float red[4];
  const int tid = threadIdx.x, lane = tid&63, wv = tid>>6;

  if (blockIdx.x < 512){
    if (t > T_STEPS) return;
    const int gid = blockIdx.x*256 + tid;     // 0..131071 (f4 index)
    const int b = gid >> 10, h0 = (gid & 1023) << 2;
    const float vth = vth_of(*hmax_t);
    float4 h = *(const float4*)(hv + (size_t)gid*4);

    if (t > 0){   // hs_{t-1} = hv_{t-1} > vth(max hv_{t-1})
      const int kc = h0>>5, kg=(h0>>3)&3, e=h0&7, r=b&15, m16l=b>>4;
      f16x4 s;
      s[0]=(h.x>vth)?(_Float16)1:(_Float16)0; s[1]=(h.y>vth)?(_Float16)1:(_Float16)0;
      s[2]=(h.z>vth)?(_Float16)1:(_Float16)0; s[3]=(h.w>vth)?(_Float16)1:(_Float16)0;
      *(f16x4*)(hs_slot + ((size_t)m16l*128 + kc)*512 + kg*128 + r*8 + e) = s;
    }
    if (t < T_STEPS){
      float4 g = *(const float4*)(Gs + (size_t)gid*4);
      float4 o;
      o.x = (h.x>vth ? 0.f : 0.5f*h.x) + g.x;
      o.y = (h.y>vth ? 0.f : 0.5f*h.y) + g.y;
      o.z = (h.z>vth ? 0.f : 0.5f*h.z) + g.z;
      o.w = (h.w>vth ? 0.f : 0.5f*h.w) + g.w;
      *(float4*)(hv + (size_t)gid*4) = o;
      float lmax = fmaxf(fmaxf(o.x,o.y),fmaxf(o.z,o.w));
      #pragma unroll
      for (int off=32; off>0; off>>=1) lmax = fmaxf(lmax, __shfl_down(lmax, off));
      if (lane==0) red[wv] = lmax;
      __syncthreads();
      if (tid==0){
        float m = fmaxf(fmaxf(red[0],red[1]),fmaxf(red[2],red[3]));
        atomicMax(hmax_n, fmap(m));
      }
    }
  } else {
    if (ovt < 0 || ovt >= TAIL_START) return;
    const int f = (int)(blockIdx.x - 512)*256 + tid;   // f4 index 0..4095
    const float vthp = vth_of(omaxA[ovt]);             // max of step ovt-1
    const int slot = ovt % RING_S;
    float lmax = -3.0e38f;
    #pragma unroll
    for (int q=0;q<4;q++){
      int o4 = f + q*4096;
      float4 v = *(const float4*)(ovs + (size_t)o4*4);
      uchar4 c = cnt8[o4];
      bool s0 = v.x > vthp, s1 = v.y > vthp, s2 = v.z > vthp, s3 = v.w > vthp;
      c.x += s0; c.y += s1; c.z += s2; c.w += s3;
      v.x = s0 ? 0.f : 0.5f*v.x;
      v.y = s1 ? 0.f : 0.5f*v.y;
      v.z = s2 ? 0.f : 0.5f*v.z;
      v.w = s3 ? 0.f : 0.5f*v.w;
      float4 g0 = *(const float4*)(OGp + ((size_t)slot*4+0)*(B_DIM*O_DIM) + (size_t)o4*4);
      float4 g1 = *(const float4*)(OGp + ((size_t)slot*4+1)*(B_DIM*O_DIM) + (size_t)o4*4);
      float4 g2 = *(const float4*)(OGp + ((size_t)slot*4+2)*(B_DIM*O_DIM) + (size_t)o4*4);
      float4 g3 = *(const float4*)(OGp + ((size_t)slot*4+3)*(B_DIM*O_DIM) + (size_t)o4*4);
      v.x += (g0.x+g1.x)+(g2.x+g3.x);
      v.y += (g0.y+g1.y)+(g2.y+g3.y);
      v.z += (g0.z+g1.z)+(g2.z+g3.z);
      v.w += (g0.w+g1.w)+(g2.w+g3.w);
      lmax = fmaxf(lmax, fmaxf(fmaxf(v.x,v.y),fmaxf(v.z,v.w)));
      *(float4*)(ovs + (size_t)o4*4) = v;
      cnt8[o4] = c;
    }
    #pragma unroll
    for (int off=32; off>0; off>>=1) lmax = fmaxf(lmax, __shfl_down(lmax, off));
    if (lane==0) red[wv] = lmax;
    __syncthreads();
    if (tid==0){
      float m = fmaxf(fmaxf(red[0],red[1]),fmaxf(red[2],red[3]));
      atomicMax(&omaxA[ovt+1], fmap(m));
    }
  }
}

// Persistent per-chunk hv chain: steps t = t0..t0+nsteps-1 (t0 = 20c+1).
// 256 blocks x 512 threads, all co-resident (tiny VGPR/LDS). hv and the ov
// rider state live in REGISTERS across steps. Grid barrier per step via the
// ov_tail-proven monotonic-counter + threadfence pattern (gctr_hv).
// Riders: gid < 16384 (blocks 0..31), 1 f4 each — same per-element math.
__global__ __launch_bounds__(512) void hv_chunk(
    const float* __restrict__ Gs,          // slice for t0 (step j at Gs + j*B*H)
    float* __restrict__ hv,
    _Float16* __restrict__ HS,
    unsigned* __restrict__ hmaxA,
    const float* __restrict__ OGp, float* __restrict__ ovs,
    uchar4* __restrict__ cnt8, unsigned* __restrict__ omaxA,
    unsigned* __restrict__ gctr, int t0, int nsteps, int bar0)
{
  __shared__ float red[8], redo[8];
  const int tid = threadIdx.x, lane = tid&63, wv = tid>>6;
  const int gid = blockIdx.x*512 + tid;          // f4 index 0..131071
  const int b = gid >> 10, h0 = (gid & 1023) << 2;
  const int kc = h0>>5, kg=(h0>>3)&3, e=h0&7, r=b&15, m16l=b>>4;
  const bool ovon = gid < (B_DIM*O_DIM/4);       // blocks 0..31

  float4 h = *(const float4*)(hv + (size_t)gid*4);
  float4 vo = make_float4(0.f,0.f,0.f,0.f);
  unsigned cw = 0;
  if (ovon){
    vo = *(const float4*)(ovs + (size_t)gid*4);
    uchar4 c0 = cnt8[gid];
    cw = (unsigned)c0.x | ((unsigned)c0.y<<8) | ((unsigned)c0.z<<16) | ((unsigned)c0.w<<24);
  }
  // prefetch G for step 0 (t0 <= 81 < 100 always)
  float4 g = *(const float4*)(Gs + (size_t)gid*4);

  for (int j = 0; j < nsteps; j++){
    const int t = t0 + j;
    const int ovt = t - OV_LAG;
    const bool last = (j == nsteps-1);

    // prefetch next step's G early (data independent of barrier)
    float4 gn = make_float4(0.f,0.f,0.f,0.f);
    if (!last && (t+1) < T_STEPS)
      gn = *(const float4*)(Gs + (size_t)(j+1)*(B_DIM*H_DIM) + (size_t)gid*4);

    const float vth = vth_of(hmaxA[t]);
    {  // hs_{t-1} emit (t0 >= 1 so t > 0 always here)
      f16x4 s;
      s[0]=(h.x>vth)?(_Float16)1:(_Float16)0; s[1]=(h.y>vth)?(_Float16)1:(_Float16)0;
      s[2]=(h.z>vth)?(_Float16)1:(_Float16)0; s[3]=(h.w>vth)?(_Float16)1:(_Float16)0;
      _Float16* slotp = HS + (size_t)((t-1)%HS_RING)*HS_SLOT;
      *(f16x4*)(slotp + ((size_t)m16l*128 + kc)*512 + kg*128 + r*8 + e) = s;
    }
    float lmax = -3.0e38f;
    if (t < T_STEPS){
      h.x = (h.x>vth ? 0.f : 0.5f*h.x) + g.x;
      h.y = (h.y>vth ? 0.f : 0.5f*h.y) + g.y;
      h.z = (h.z>vth ? 0.f : 0.5f*h.z) + g.z;
      h.w = (h.w>vth ? 0.f : 0.5f*h.w) + g.w;
      lmax = fmaxf(fmaxf(h.x,h.y),fmaxf(h.z,h.w));
    }

    float omax_l = -3.0e38f;
    if (ovon && ovt >= 0 && ovt < TAIL_START){
      const float vthp = vth_of(omaxA[ovt]);
      const int slot = ovt % RING_S;
      bool s0 = vo.x > vthp, s1 = vo.y > vthp, s2 = vo.z > vthp, s3 = vo.w > vthp;
      cw += (s0?1u:0u) | (s1?(1u<<8):0u) | (s2?(1u<<16):0u) | (s3?(1u<<24):0u);
      vo.x = s0 ? 0.f : 0.5f*vo.x;
      vo.y = s1 ? 0.f : 0.5f*vo.y;
      vo.z = s2 ? 0.f : 0.5f*vo.z;
      vo.w = s3 ? 0.f : 0.5f*vo.w;
      float4 g0 = *(const float4*)(OGp + ((size_t)slot*4+0)*(B_DIM*O_DIM) + (size_t)gid*4);
      float4 g1 = *(const float4*)(OGp + ((size_t)slot*4+1)*(B_DIM*O_DIM) + (size_t)gid*4);
      float4 g2 = *(const float4*)(OGp + ((size_t)slot*4+2)*(B_DIM*O_DIM) + (size_t)gid*4);
      float4 g3 = *(const float4*)(OGp + ((size_t)slot*4+3)*(B_DIM*O_DIM) + (size_t)gid*4);
      vo.x += (g0.x+g1.x)+(g2.x+g3.x);
      vo.y += (g0.y+g1.y)+(g2.y+g3.y);
      vo.z += (g0.z+g1.z)+(g2.z+g3.z);
      vo.w += (g0.w+g1.w)+(g2.w+g3.w);
      omax_l = fmaxf(fmaxf(vo.x,vo.y),fmaxf(vo.z,vo.w));
    }

    // block reductions
    #pragma unroll
    for (int off2=32; off2>0; off2>>=1) lmax = fmaxf(lmax, __shfl_down(lmax, off2));
    if (lane==0) red[wv] = lmax;
    if (ovon){
      #pragma unroll
      for (int off2=32; off2>0; off2>>=1) omax_l = fmaxf(omax_l, __shfl_down(omax_l, off2));
      if (lane==0) redo[wv] = omax_l;
    }
    __syncthreads();
    if (tid == 0){
      if (t < T_STEPS){
        float m = red[0];
        #pragma unroll
        for (int w2=1; w2<8; w2++) m = fmaxf(m, red[w2]);
        atomicMax(&hmaxA[t+1], fmap(m));
      }
      if (blockIdx.x < 32 && ovt >= 0 && ovt < TAIL_START){
        float mo = redo[0];
        #pragma unroll
        for (int w2=1; w2<8; w2++) mo = fmaxf(mo, redo[w2]);
        atomicMax(&omaxA[ovt+1], fmap(mo));
      }
      if (!last){
        __threadfence();
        atomicAdd(gctr, 1u);
        unsigned target = (unsigned)(bar0 + j + 1) * 256u;
        while (__hip_atomic_load(gctr, __ATOMIC_RELAXED, __HIP_MEMORY_SCOPE_AGENT) < target)
          __builtin_amdgcn_s_sleep(1);
        __threadfence();
      }
    }
    __syncthreads();
    g = gn;
  }

  *(float4*)(hv + (size_t)gid*4) = h;
  if (ovon){
    *(float4*)(ovs + (size_t)gid*4) = vo;
    cnt8[gid] = make_uchar4((unsigned char)(cw & 0xffu),
                            (unsigned char)((cw>>8) & 0xffu),
                            (unsigned char)((cw>>16) & 0xffu),
                            (unsigned char)((cw>>24) & 0xffu));
  }
}

// Batched GEMM2 v3: 4-way K-split. OGp[(s%RING_S)*4 + kh] = HS[s] @ Wo^T over
// K-quarter kh. gemm1-style async-LDS double buffer.
__global__ __launch_bounds__(256, 2) void gemm2_mfma(
    const _Float16* __restrict__ HS,
    const _Float16* __restrict__ WoHi, const _Float16* __restrict__ WoLo,
    float* __restrict__ OGp, int c)
{
  __shared__ __align__(16) _Float16 lds2[2][24][512];   // 48 KB
  const int tid = threadIdx.x, wave = tid>>6, lane = tid&63;
  const int bn = blockIdx.x, bm = blockIdx.y, kh = blockIdx.z;
  const int s = c*T_CHUNK + bm, ring = s % HS_RING;
  const int wm = wave>>1, wn = wave&1;
  const int kc0 = kh*32;

  const _Float16* baseA = HS   + (size_t)ring*8*128*512 + lane*8;
  const _Float16* baseH = WoHi + (size_t)bn*8*128*512 + lane*8;
  const _Float16* baseL = WoLo + (size_t)bn*8*128*512 + lane*8;

  f32x4 acc[16];
  #pragma unroll
  for (int i=0;i<16;i++) acc[i] = (f32x4){0.f,0.f,0.f,0.f};

  #pragma unroll
  for (int i=0;i<6;i++){
    int f = wave*6 + i;
    const _Float16* g = (f<8)  ? baseA + ((size_t)f*128      + kc0)*512
                     : (f<16) ? baseH + ((size_t)(f-8)*128  + kc0)*512
                              : baseL + ((size_t)(f-16)*128 + kc0)*512;
    gload_lds16(g, &lds2[0][f][0]);
  }

  for (int k=0;k<32;k++){
    __syncthreads();              // vmcnt drain + barrier: buf[k&1] ready
    if (k < 31){
      #pragma unroll
      for (int i=0;i<6;i++){
        int f = wave*6 + i;
        const _Float16* g = (f<8)  ? baseA + ((size_t)f*128      + kc0+k+1)*512
                         : (f<16) ? baseH + ((size_t)(f-8)*128  + kc0+k+1)*512
                                  : baseL + ((size_t)(f-16)*128 + kc0+k+1)*512;
        gload_lds16(g, &lds2[(k+1)&1][f][0]);
      }
    }
    const int cb = k&1;
    f16x8 fA[4], fH[4], fL[4];
    #pragma unroll
    for (int i=0;i<4;i++){
      fA[i] = *(const f16x8*)&lds2[cb][wm*4+i][lane*8];
      fH[i] = *(const f16x8*)&lds2[cb][8+wn*4+i][lane*8];
      fL[i] = *(const f16x8*)&lds2[cb][16+wn*4+i][lane*8];
    }
    #pragma unroll
    for (int i=0;i<4;i++)
      #pragma unroll
      for (int j=0;j<4;j++)
        acc[i*4+j] = __builtin_amdgcn_mfma_f32_16x16x32_f16(fA[i], fH[j], acc[i*4+j], 0,0,0);
    #pragma unroll
    for (int i=0;i<4;i++)
      #pragma unroll
      for (int j=0;j<4;j++)
        acc[i*4+j] = __builtin_amdgcn_mfma_f32_16x16x32_f16(fA[i], fL[j], acc[i*4+j], 0,0,0);
  }
  const int colw = lane&15, quad = lane>>4;
  const float sc = 1.f/256.f;
  float* eds = (float*)lds2 + wave*2048;
  __syncthreads();
  float* OGd = OGp + ((size_t)(s % RING_S)*4 + kh)*(B_DIM*O_DIM);
  #pragma unroll
  for (int ih=0; ih<2; ih++){
    #pragma unroll
    for (int il=0; il<2; il++){
      int i = ih*2+il;
      #pragma unroll
      for (int j=0;j<4;j++)
        #pragma unroll
        for (int r=0;r<4;r++)
          eds[(il*16 + quad*4 + r)*64 + j*16 + colw] = acc[i*4+j][r]*sc;
    }
    #pragma unroll
    for (int rr8=0; rr8<8; rr8++){
      int row = rr8*4 + quad;
      float4 v = *(float4*)&eds[row*64 + colw*4];
      int m = wm*64 + ih*32 + row;
      int n = bn*128 + wn*64 + colw*4;
      *(float4*)&OGd[(size_t)m*O_DIM + n] = v;
    }
  }
}

// Tail: ov steps TAIL_START..T_STEPS in ONE 16-block persistent kernel.
__global__ __launch_bounds__(256) void ov_tail(
    const float* __restrict__ OGp, const float* __restrict__ ovs,
    const uchar4* __restrict__ cnt8, unsigned* __restrict__ omaxA,
    unsigned* __restrict__ gctr, float* __restrict__ out)
{
  __shared__ float red[4];
  const int tid = threadIdx.x, lane = tid&63, wv = tid>>6;
  const int f = blockIdx.x*256 + tid;
  float ov[16];
  unsigned cw[4];          // byte-packed counts per 4-group
  #pragma unroll
  for (int q=0;q<4;q++){
    int o4 = f + q*4096;
    float4 v = *(const float4*)(ovs + (size_t)o4*4);
    ov[q*4+0]=v.x; ov[q*4+1]=v.y; ov[q*4+2]=v.z; ov[q*4+3]=v.w;
    uchar4 c = cnt8[o4];
    cw[q] = (unsigned)c.x | ((unsigned)c.y<<8) | ((unsigned)c.z<<16) | ((unsigned)c.w<<24);
  }
  unsigned bar = 0;

  for (int ovt = TAIL_START; ovt <= T_STEPS; ovt++){
    const float vth = vth_of(omaxA[ovt]);
    const int slot = ovt % RING_S;
    float lmax = -3.0e38f;
    #pragma unroll
    for (int q=0;q<4;q++){
      int o4 = f + q*4096;
      #pragma unroll
      for (int e=0;e<4;e++){
        int idx = q*4+e;
        bool os = ov[idx] > vth;
        cw[q] += os ? (1u<<(e*8)) : 0u;
        ov[idx] = os ? 0.f : 0.5f*ov[idx];
      }
      if (ovt < T_STEPS){
        float4 g0 = *(const float4*)(OGp + ((size_t)slot*4+0)*(B_DIM*O_DIM) + (size_t)o4*4);
        float4 g1 = *(const float4*)(OGp + ((size_t)slot*4+1)*(B_DIM*O_DIM) + (size_t)o4*4);
        float4 g2 = *(const float4*)(OGp + ((size_t)slot*4+2)*(B_DIM*O_DIM) + (size_t)o4*4);
        float4 g3 = *(const float4*)(OGp + ((size_t)slot*4+3)*(B_DIM*O_DIM) + (size_t)o4*4);
        ov[q*4+0] += (g0.x+g1.x)+(g2.x+g3.x);
        ov[q*4+1] += (g0.y+g1.y)+(g2.y+g3.y);
        ov[q*4+2] += (g0.z+g1.z)+(g2.z+g3.z);
        ov[q*4+3] += (g0.w+g1.w)+(g2.w+g3.w);
        lmax = fmaxf(lmax, fmaxf(fmaxf(ov[q*4+0],ov[q*4+1]),fmaxf(ov[q*4+2],ov[q*4+3])));
      }
    }
    if (ovt == T_STEPS) break;    // last step: spike-only, no sync needed
    #pragma unroll
    for (int off=32; off>0; off>>=1) lmax = fmaxf(lmax, __shfl_down(lmax, off));
    if (lane==0) red[wv] = lmax;
    __syncthreads();
    if (tid==0){
      float m = fmaxf(fmaxf(red[0],red[1]),fmaxf(red[2],red[3]));
      atomicMax(&omaxA[ovt+1], fmap(m));
      __threadfence();
      atomicAdd(gctr, 1u);
      unsigned target = (++bar)*16;
      while (__hip_atomic_load(gctr, __ATOMIC_RELAXED, __HIP_MEMORY_SCOPE_AGENT) < target)
        __builtin_amdgcn_s_sleep(1);
      __threadfence();
    }
    __syncthreads();
    if (tid!=0) bar++;            // keep bar consistent across threads
  }
  #pragma unroll
  for (int q=0;q<4;q++){
    int o4 = f + q*4096;
    *(float4*)(out + (size_t)o4*4) = make_float4(
        (float)( cw[q]        & 0xffu),
        (float)((cw[q] >> 8)  & 0xffu),
        (float)((cw[q] >> 16) & 0xffu),
        (float)((cw[q] >> 24) & 0xffu));
  }
}

extern "C" void kernel_launch(void* const* d_in, const int* in_sizes, int n_in,
                              void* d_out, int out_size, void* d_ws, size_t ws_size,
                              hipStream_t stream) {
  const float* spike = (const float*)d_in[0];
  const float* Wh    = (const float*)d_in[5];   // [H, I]
  const float* Wo    = (const float*)d_in[6];   // [O, H]
  float* out = (float*)d_out;

  char* ws = (char*)d_ws;
  size_t off = 0;
  _Float16* XAhi = (_Float16*)(ws+off); off += (size_t)T_CHUNK*B_DIM*I_DIM*2;
  _Float16* XAlo = (_Float16*)(ws+off); off += (size_t)T_CHUNK*B_DIM*I_DIM*2;
  _Float16* WHhi = (_Float16*)(ws+off); off += (size_t)H_DIM*I_DIM*2;
  _Float16* WHlo = (_Float16*)(ws+off); off += (size_t)H_DIM*I_DIM*2;
  _Float16* WOhi = (_Float16*)(ws+off); off += (size_t)O_DIM*H_DIM*2;
  _Float16* WOlo = (_Float16*)(ws+off); off += (size_t)O_DIM*H_DIM*2;
  float* G  = (float*)(ws+off);         off += (size_t)T_CHUNK*B_DIM*H_DIM*4;
  float* hv = (float*)(ws+off);         off += (size_t)B_DIM*H_DIM*4;
  _Float16* HS = (_Float16*)(ws+off);   off += (size_t)HS_RING*HS_SLOT*2;
  float* OGp = (float*)(ws+off);        off += (size_t)RING_S*4*B_DIM*O_DIM*4;
  float* ovs = (float*)(ws+off);        off += (size_t)B_DIM*O_DIM*4;
  uchar4* cnt8 = (uchar4*)(ws+off);     off += (size_t)B_DIM*O_DIM;
  unsigned* hmaxA = (unsigned*)(ws+off); off += 128*4;
  unsigned* omaxA = (unsigned*)(ws+off); off += 128*4;
  unsigned* gctr  = (unsigned*)(ws+off); off += 64*4;
  (void)ws_size; (void)in_sizes; (void)n_in; (void)out_size;

  init_kernel<<<(B_DIM*H_DIM+255)/256, 256, 0, stream>>>(
      hv, ovs, (uint32_t*)cnt8, hmaxA, omaxA, gctr);
  prep_weights<<<288, 256, 0, stream>>>(Wh, Wo, WHhi, WHlo, WOhi, WOlo);

  for (int c = 0; c < T_STEPS/T_CHUNK; c++){
    prep_x<<<dim3(8,32,2), 256, 0, stream>>>(spike, XAhi, XAlo, c*T_CHUNK);
    gemm1_mfma<<<dim3(32, T_CHUNK), 256, 0, stream>>>(XAhi, XAlo, WHhi, WHlo, G);
    // first step of the chunk (t = 20c): emits hs_{20c-1}, needed by gemm2(c-1)
    {
      int t = c*T_CHUNK;
      int ring = (t == 0) ? (HS_RING-1) : ((t-1) % HS_RING);
      hv_step<<<528, 256, 0, stream>>>(
          G, hv, HS + (size_t)ring*HS_SLOT,
          hmaxA + t, hmaxA + t + 1, t,
          OGp, ovs, cnt8, omaxA, t - OV_LAG);
    }
    if (c > 0)
      gemm2_mfma<<<dim3(4, T_CHUNK, 4), 256, 0, stream>>>(HS, WOhi, WOlo, OGp, c-1);
    // persistent remainder of the chunk: t = 20c+1 .. 20c+19 (+ t=100 for c=4)
    {
      int nsteps = (c == T_STEPS/T_CHUNK - 1) ? T_CHUNK : (T_CHUNK - 1);
      hv_chunk<<<256, 512, 0, stream>>>(
          G + (size_t)B_DIM*H_DIM, hv, HS, hmaxA,
          OGp, ovs, cnt8, omaxA, gctr + 32,
          c*T_CHUNK + 1, nsteps, c*(T_CHUNK-2));
    }
  }
  gemm2_mfma<<<dim3(4, T_CHUNK, 4), 256, 0, stream>>>(HS, WOhi, WOlo, OGp, T_STEPS/T_CHUNK - 1);
  ov_tail<<<16, 256, 0, stream>>>(OGp, ovs, cnt8, omaxA, gctr, out);
}

// Round 3
// 1126.817 us; speedup vs baseline: 2.8823x; 2.8823x over previous
//
#include <hip/hip_runtime.h>
#include <math.h>
#include <stdint.h>

#define T_STEPS 100
#define B_DIM 128
#define I_DIM 1024
#define H_DIM 4096
#define O_DIM 512
#define T_CHUNK 20
#define HS_RING 21
#define HS_SLOT ((size_t)8*128*512)   // f16 per t-slot (8 m16-tiles x 128 kc x 512)
#define OV_LAG 21                     // ov step t' rides on hv step t = t'+21
#define RING_S 40                     // OG partial ring: 40 t-slots x 4 K-planes
#define TAIL_START 80                 // ov steps >= 80 handled by ov_tail
#define LEADER 255                    // hv_chunk aggregator block (non-rider)

typedef _Float16 f16x8 __attribute__((ext_vector_type(8)));
typedef _Float16 f16x4 __attribute__((ext_vector_type(4)));
typedef float    f32x4 __attribute__((ext_vector_type(4)));

#define AS1 __attribute__((address_space(1)))
#define AS3 __attribute__((address_space(3)))

#define ALOAD(p)    __hip_atomic_load((p), __ATOMIC_RELAXED, __HIP_MEMORY_SCOPE_AGENT)
#define ASTORE(p,v) __hip_atomic_store((p), (v), __ATOMIC_RELAXED, __HIP_MEMORY_SCOPE_AGENT)

// Async global->LDS, 16B/lane. LDS dest is wave-uniform base + lane*16,
// which exactly matches the 1KB fragment-block layout (64 lanes x 16B).
__device__ __forceinline__ void gload_lds16(const _Float16* g, _Float16* l){
  __builtin_amdgcn_global_load_lds(
      (const AS1 unsigned*)(uintptr_t)g,
      (AS3 unsigned*)(unsigned)(uintptr_t)l, 16, 0, 0);
}

// Order-preserving float->unsigned map. fmap(x) == 0 only for negative NaN,
// which never occurs => 0 is a safe "unpublished" sentinel, and 0 acts as -inf
// under unsigned max (all real floats map >= fmap(-FLT_MAX) > 0).
__device__ __forceinline__ unsigned fmap(float f){
  unsigned u = __float_as_uint(f);
  return (u & 0x80000000u) ? ~u : (u | 0x80000000u);
}
__device__ __forceinline__ float funmap(unsigned m){
  unsigned u = (m & 0x80000000u) ? (m & 0x7FFFFFFFu) : ~m;
  return __uint_as_float(u);
}
__device__ __forceinline__ float vth_of(unsigned m){
  return 0.3f * tanhf(0.3f * funmap(m));
}

__global__ __launch_bounds__(256) void init_kernel(float* hv, float* ovs,
                                                   uint32_t* cnt32,
                                                   unsigned* hmaxA, unsigned* omaxA,
                                                   unsigned* hflag, unsigned* oflag)
{
  int i = blockIdx.x * 256 + threadIdx.x;
  if (i < B_DIM*H_DIM) hv[i] = 0.f;
  if (i < B_DIM*O_DIM) ovs[i] = 0.f;
  if (i < B_DIM*O_DIM/4) cnt32[i] = 0u;
  if (i < 100*256) hflag[i] = 0u;
  if (i < 101*32)  oflag[i] = 0u;
  if (i < 128){
    // slot0 = "max of zero state" -> fmap(0) -> vth 0 -> spike(0>0)=0.
    // all other slots: 0 sentinel = unpublished (acts as -inf for atomicMax).
    unsigned v = (i==0) ? 0x80000000u : 0u;
    hmaxA[i] = v; omaxA[i] = v;
  }
}

// spike_data [B][I][T] fp32 -> fragment-tiled f16 hi/lo of (x*2048), chunk of 20 t.
__global__ __launch_bounds__(256) void prep_x(const float* __restrict__ sp,
                                              _Float16* __restrict__ Ahi,
                                              _Float16* __restrict__ Alo, int t0)
{
  __shared__ float tile[32][16][10];
  const int b16 = blockIdx.x, kc = blockIdx.y, tz = blockIdx.z;
  for (int e = threadIdx.x; e < 5120; e += 256){
    int tt = e % 10, row = e / 10;
    int bb = row >> 5, ii = row & 31;
    tile[ii][bb][tt] =
      sp[((size_t)(b16*16+bb)*I_DIM + kc*32 + ii)*T_STEPS + t0 + tz*10 + tt];
  }
  __syncthreads();
  for (int u = threadIdx.x; u < 640; u += 256){
    int tl = u >> 6, l = u & 63, kg = l >> 4, r = l & 15;
    f16x8 hi, lo;
    #pragma unroll
    for (int e=0;e<8;e++){
      float x = tile[kg*8+e][r][tl] * 2048.f;
      _Float16 h = (_Float16)x;
      hi[e] = h;
      lo[e] = (_Float16)(x - (float)h);
    }
    int t_local = tz*10 + tl;
    size_t off = ((size_t)(t_local*8 + b16)*32 + kc)*512 + kg*128 + r*8;
    *(f16x8*)(Ahi + off) = hi;
    *(f16x8*)(Alo + off) = lo;
  }
}

// Wh [H][I] and Wo [O][H] fp32 -> FB-tiled f16 hi/lo of (w*256), one launch.
__global__ __launch_bounds__(256) void prep_weights(
    const float* __restrict__ Wh, const float* __restrict__ Wo,
    _Float16* __restrict__ WHhi, _Float16* __restrict__ WHlo,
    _Float16* __restrict__ WOhi, _Float16* __restrict__ WOlo)
{
  const int blk = blockIdx.x;
  if (blk < 256){
    const int n16 = blk;
    for (int u = threadIdx.x; u < 2048; u += 256){
      int kc = u >> 6, l = u & 63, kg = l >> 4, r = l & 15;
      const float* src = Wh + (size_t)(n16*16 + r)*I_DIM + kc*32 + kg*8;
      f16x8 hi, lo;
      #pragma unroll
      for (int e=0;e<8;e++){
        float x = src[e] * 256.f;
        _Float16 h = (_Float16)x;
        hi[e] = h; lo[e] = (_Float16)(x - (float)h);
      }
      size_t off = ((size_t)n16*32 + kc)*512 + kg*128 + r*8;
      *(f16x8*)(WHhi + off) = hi;
      *(f16x8*)(WHlo + off) = lo;
    }
  } else {
    const int n16 = blk - 256;
    for (int u = threadIdx.x; u < 8192; u += 256){
      int kc = u >> 6, l = u & 63, kg = l >> 4, r = l & 15;
      const float* src = Wo + (size_t)(n16*16 + r)*H_DIM + kc*32 + kg*8;
      f16x8 hi, lo;
      #pragma unroll
      for (int e=0;e<8;e++){
        float x = src[e] * 256.f;
        _Float16 h = (_Float16)x;
        hi[e] = h; lo[e] = (_Float16)(x - (float)h);
      }
      size_t off = ((size_t)(n16*128 + kc))*512 + kg*128 + r*8;
      *(f16x8*)(WOhi + off) = hi;
      *(f16x8*)(WOlo + off) = lo;
    }
  }
}

// Batched GEMM1 (chunk of 20 t): G = XT @ Wh^T via fp16x3 exact-split MFMA.
__global__ __launch_bounds__(256, 2) void gemm1_mfma(
    const _Float16* __restrict__ Ahi, const _Float16* __restrict__ Alo,
    const _Float16* __restrict__ Bhi, const _Float16* __restrict__ Blo,
    float* __restrict__ G)
{
  __shared__ __align__(16) _Float16 lds[2][4][8][512];   // 64 KB, 2 blocks/CU
  const int tid = threadIdx.x, wave = tid>>6, lane = tid&63;
  const int bn = blockIdx.x, bm = blockIdx.y;
  const int wm = wave>>1, wn = wave&1;

  const _Float16* srcbase = (wave==0)?Ahi:(wave==1)?Alo:(wave==2)?Bhi:Blo;
  const int r16b = ((wave<2) ? bm : bn)*8;
  const _Float16* gsrc = srcbase + (size_t)r16b*32*512 + lane*8;

  f32x4 acc[16];
  #pragma unroll
  for (int i=0;i<16;i++) acc[i] = (f32x4){0.f,0.f,0.f,0.f};

  #pragma unroll
  for (int q=0;q<8;q++)
    gload_lds16(gsrc + (size_t)q*32*512, &lds[0][wave][q][0]);

  for (int kc=0;kc<32;kc++){
    __syncthreads();
    if (kc < 31){
      #pragma unroll
      for (int q=0;q<8;q++)
        gload_lds16(gsrc + ((size_t)q*32 + kc+1)*512, &lds[(kc+1)&1][wave][q][0]);
    }
    const int cb = kc&1;
    f16x8 fAh[4], fAl[4], fBh[4], fBl[4];
    #pragma unroll
    for (int i=0;i<4;i++){
      fAh[i] = *(const f16x8*)&lds[cb][0][wm*4+i][lane*8];
      fAl[i] = *(const f16x8*)&lds[cb][1][wm*4+i][lane*8];
      fBh[i] = *(const f16x8*)&lds[cb][2][wn*4+i][lane*8];
      fBl[i] = *(const f16x8*)&lds[cb][3][wn*4+i][lane*8];
    }
    #pragma unroll
    for (int i=0;i<4;i++)
      #pragma unroll
      for (int j=0;j<4;j++)
        acc[i*4+j] = __builtin_amdgcn_mfma_f32_16x16x32_f16(fAh[i], fBh[j], acc[i*4+j], 0,0,0);
    #pragma unroll
    for (int i=0;i<4;i++)
      #pragma unroll
      for (int j=0;j<4;j++)
        acc[i*4+j] = __builtin_amdgcn_mfma_f32_16x16x32_f16(fAh[i], fBl[j], acc[i*4+j], 0,0,0);
    #pragma unroll
    for (int i=0;i<4;i++)
      #pragma unroll
      for (int j=0;j<4;j++)
        acc[i*4+j] = __builtin_amdgcn_mfma_f32_16x16x32_f16(fAl[i], fBh[j], acc[i*4+j], 0,0,0);
  }
  const int colw = lane&15, quad = lane>>4;
  const float sc = 1.f/(2048.f*256.f);
  float* eds = (float*)lds + wave*2048;
  __syncthreads();
  #pragma unroll
  for (int ih=0; ih<2; ih++){
    #pragma unroll
    for (int il=0; il<2; il++){
      int i = ih*2+il;
      #pragma unroll
      for (int j=0;j<4;j++)
        #pragma unroll
        for (int r=0;r<4;r++)
          eds[(il*16 + quad*4 + r)*64 + j*16 + colw] = acc[i*4+j][r]*sc;
    }
    #pragma unroll
    for (int rr8=0; rr8<8; rr8++){
      int row = rr8*4 + quad;
      float4 v = *(float4*)&eds[row*64 + colw*4];
      int m = bm*128 + wm*64 + ih*32 + row;
      int n = bn*128 + wn*64 + colw*4;
      *(float4*)&G[(size_t)m*H_DIM + n] = v;
    }
  }
}

// Per-chunk FIRST step only (t = 20c), 528 blocks. atomicMax publish is fine
// here: once per chunk, not on the per-step critical path.
__global__ __launch_bounds__(256) void hv_step(
    const float* __restrict__ Gs, float* __restrict__ hv,
    _Float16* __restrict__ hs_slot,
    const unsigned* __restrict__ hmax_t, unsigned* __restrict__ hmax_n, int t,
    const float* __restrict__ OGp, float* __restrict__ ovs,
    uchar4* __restrict__ cnt8, unsigned* __restrict__ omaxA, int ovt)
{
  __shared__ float red[4];
  const int tid = threadIdx.x, lane = tid&63, wv = tid>>6;

  if (blockIdx.x < 512){
    if (t > T_STEPS) return;
    const int gid = blockIdx.x*256 + tid;     // 0..131071 (f4 index)
    const int b = gid >> 10, h0 = (gid & 1023) << 2;
    const float vth = vth_of(*hmax_t);
    float4 h = *(const float4*)(hv + (size_t)gid*4);

    if (t > 0){   // hs_{t-1} = hv_{t-1} > vth(max hv_{t-1})
      const int kc = h0>>5, kg=(h0>>3)&3, e=h0&7, r=b&15, m16l=b>>4;
      f16x4 s;
      s[0]=(h.x>vth)?(_Float16)1:(_Float16)0; s[1]=(h.y>vth)?(_Float16)1:(_Float16)0;
      s[2]=(h.z>vth)?(_Float16)1:(_Float16)0; s[3]=(h.w>vth)?(_Float16)1:(_Float16)0;
      *(f16x4*)(hs_slot + ((size_t)m16l*128 + kc)*512 + kg*128 + r*8 + e) = s;
    }
    if (t < T_STEPS){
      float4 g = *(const float4*)(Gs + (size_t)gid*4);
      float4 o;
      o.x = (h.x>vth ? 0.f : 0.5f*h.x) + g.x;
      o.y = (h.y>vth ? 0.f : 0.5f*h.y) + g.y;
      o.z = (h.z>vth ? 0.f : 0.5f*h.z) + g.z;
      o.w = (h.w>vth ? 0.f : 0.5f*h.w) + g.w;
      *(float4*)(hv + (size_t)gid*4) = o;
      float lmax = fmaxf(fmaxf(o.x,o.y),fmaxf(o.z,o.w));
      #pragma unroll
      for (int off=32; off>0; off>>=1) lmax = fmaxf(lmax, __shfl_down(lmax, off));
      if (lane==0) red[wv] = lmax;
      __syncthreads();
      if (tid==0){
        float m = fmaxf(fmaxf(red[0],red[1]),fmaxf(red[2],red[3]));
        atomicMax(hmax_n, fmap(m));
      }
    }
  } else {
    if (ovt < 0 || ovt >= TAIL_START) return;
    const int f = (int)(blockIdx.x - 512)*256 + tid;   // f4 index 0..4095
    const float vthp = vth_of(omaxA[ovt]);             // max of step ovt-1
    const int slot = ovt % RING_S;
    float lmax = -3.0e38f;
    #pragma unroll
    for (int q=0;q<4;q++){
      int o4 = f + q*4096;
      float4 v = *(const float4*)(ovs + (size_t)o4*4);
      uchar4 c = cnt8[o4];
      bool s0 = v.x > vthp, s1 = v.y > vthp, s2 = v.z > vthp, s3 = v.w > vthp;
      c.x += s0; c.y += s1; c.z += s2; c.w += s3;
      v.x = s0 ? 0.f : 0.5f*v.x;
      v.y = s1 ? 0.f : 0.5f*v.y;
      v.z = s2 ? 0.f : 0.5f*v.z;
      v.w = s3 ? 0.f : 0.5f*v.w;
      float4 g0 = *(const float4*)(OGp + ((size_t)slot*4+0)*(B_DIM*O_DIM) + (size_t)o4*4);
      float4 g1 = *(const float4*)(OGp + ((size_t)slot*4+1)*(B_DIM*O_DIM) + (size_t)o4*4);
      float4 g2 = *(const float4*)(OGp + ((size_t)slot*4+2)*(B_DIM*O_DIM) + (size_t)o4*4);
      float4 g3 = *(const float4*)(OGp + ((size_t)slot*4+3)*(B_DIM*O_DIM) + (size_t)o4*4);
      v.x += (g0.x+g1.x)+(g2.x+g3.x);
      v.y += (g0.y+g1.y)+(g2.y+g3.y);
      v.z += (g0.z+g1.z)+(g2.z+g3.z);
      v.w += (g0.w+g1.w)+(g2.w+g3.w);
      lmax = fmaxf(lmax, fmaxf(fmaxf(v.x,v.y),fmaxf(v.z,v.w)));
      *(float4*)(ovs + (size_t)o4*4) = v;
      cnt8[o4] = c;
    }
    #pragma unroll
    for (int off=32; off>0; off>>=1) lmax = fmaxf(lmax, __shfl_down(lmax, off));
    if (lane==0) red[wv] = lmax;
    __syncthreads();
    if (tid==0){
      float m = fmaxf(fmaxf(red[0],red[1]),fmaxf(red[2],red[3]));
      atomicMax(&omaxA[ovt+1], fmap(m));
    }
  }
}

// Persistent per-chunk hv chain: steps t = t0..t0+nsteps-1 (t0 = 20c+1).
// 256 blocks x 512 threads, co-resident. hv + rider state in registers.
// Per-step sync: single-writer flag protocol, ZERO same-line atomic RMW.
//   1. each block stores fmap(blockmax) to its own hflag[t*256+blk] word
//   2. LEADER block: 256 lanes poll the flags (value!=0 = published), umax
//      reduce (fmap is order-preserving), single store -> hmaxA[t+1];
//      wave 4 does the same for the 32 rider oflag words -> omaxA[ovt+1]
//   3. all blocks poll hmaxA[t+1] != 0; the value IS the broadcast payload.
__global__ __launch_bounds__(512) void hv_chunk(
    const float* __restrict__ Gs,          // slice for t0 (step j at Gs + j*B*H)
    float* __restrict__ hv,
    _Float16* __restrict__ HS,
    unsigned* __restrict__ hmaxA,
    const float* __restrict__ OGp, float* __restrict__ ovs,
    uchar4* __restrict__ cnt8, unsigned* __restrict__ omaxA,
    unsigned* __restrict__ hflag, unsigned* __restrict__ oflag,
    int t0, int nsteps)
{
  __shared__ float red[8], redo[8];
  __shared__ unsigned sredH[4];
  __shared__ unsigned sh_h, sh_o;
  const int tid = threadIdx.x, lane = tid&63, wv = tid>>6;
  const int blk = blockIdx.x;
  const int gid = blk*512 + tid;                 // f4 index 0..131071
  const int b = gid >> 10, h0 = (gid & 1023) << 2;
  const int kc = h0>>5, kg=(h0>>3)&3, e=h0&7, r=b&15, m16l=b>>4;
  const bool ovblk = blk < 32;                   // rider blocks (gid < 16384)

  float4 h = *(const float4*)(hv + (size_t)gid*4);
  float4 vo = make_float4(0.f,0.f,0.f,0.f);
  unsigned cw = 0;
  if (ovblk){
    vo = *(const float4*)(ovs + (size_t)gid*4);
    uchar4 c0 = cnt8[gid];
    cw = (unsigned)c0.x | ((unsigned)c0.y<<8) | ((unsigned)c0.z<<16) | ((unsigned)c0.w<<24);
  }
  float4 g = *(const float4*)(Gs + (size_t)gid*4);   // step 0's G
  unsigned hm_cur = hmaxA[t0];                       // complete at kernel entry
  unsigned om_cur = 0;
  { int ovt0 = t0 - OV_LAG;
    if (ovblk && ovt0 >= 0 && ovt0 < TAIL_START) om_cur = omaxA[ovt0]; }

  for (int j = 0; j < nsteps; j++){
    const int t = t0 + j;
    const int ovt = t - OV_LAG;
    const bool last = (j == nsteps-1);

    // prefetch next step's G early (independent of the barrier)
    float4 gn = make_float4(0.f,0.f,0.f,0.f);
    if (!last && (t+1) < T_STEPS)
      gn = *(const float4*)(Gs + (size_t)(j+1)*(B_DIM*H_DIM) + (size_t)gid*4);

    const float vth = vth_of(hm_cur);
    {  // hs_{t-1} emit (t0 >= 1 so t > 0 always here)
      f16x4 s;
      s[0]=(h.x>vth)?(_Float16)1:(_Float16)0; s[1]=(h.y>vth)?(_Float16)1:(_Float16)0;
      s[2]=(h.z>vth)?(_Float16)1:(_Float16)0; s[3]=(h.w>vth)?(_Float16)1:(_Float16)0;
      _Float16* slotp = HS + (size_t)((t-1)%HS_RING)*HS_SLOT;
      *(f16x4*)(slotp + ((size_t)m16l*128 + kc)*512 + kg*128 + r*8 + e) = s;
    }
    float lmax = -3.0e38f;
    if (t < T_STEPS){
      h.x = (h.x>vth ? 0.f : 0.5f*h.x) + g.x;
      h.y = (h.y>vth ? 0.f : 0.5f*h.y) + g.y;
      h.z = (h.z>vth ? 0.f : 0.5f*h.z) + g.z;
      h.w = (h.w>vth ? 0.f : 0.5f*h.w) + g.w;
      lmax = fmaxf(fmaxf(h.x,h.y),fmaxf(h.z,h.w));
    }

    const bool rid = ovblk && ovt >= 0 && ovt < TAIL_START;
    float omax_l = -3.0e38f;
    if (rid){
      const float vthp = vth_of(om_cur);
      const int slot = ovt % RING_S;
      bool s0 = vo.x > vthp, s1 = vo.y > vthp, s2 = vo.z > vthp, s3 = vo.w > vthp;
      cw += (s0?1u:0u) | (s1?(1u<<8):0u) | (s2?(1u<<16):0u) | (s3?(1u<<24):0u);
      vo.x = s0 ? 0.f : 0.5f*vo.x;
      vo.y = s1 ? 0.f : 0.5f*vo.y;
      vo.z = s2 ? 0.f : 0.5f*vo.z;
      vo.w = s3 ? 0.f : 0.5f*vo.w;
      float4 g0 = *(const float4*)(OGp + ((size_t)slot*4+0)*(B_DIM*O_DIM) + (size_t)gid*4);
      float4 g1 = *(const float4*)(OGp + ((size_t)slot*4+1)*(B_DIM*O_DIM) + (size_t)gid*4);
      float4 g2 = *(const float4*)(OGp + ((size_t)slot*4+2)*(B_DIM*O_DIM) + (size_t)gid*4);
      float4 g3 = *(const float4*)(OGp + ((size_t)slot*4+3)*(B_DIM*O_DIM) + (size_t)gid*4);
      vo.x += (g0.x+g1.x)+(g2.x+g3.x);
      vo.y += (g0.y+g1.y)+(g2.y+g3.y);
      vo.z += (g0.z+g1.z)+(g2.z+g3.z);
      vo.w += (g0.w+g1.w)+(g2.w+g3.w);
      omax_l = fmaxf(fmaxf(vo.x,vo.y),fmaxf(vo.z,vo.w));
    }

    // block reductions
    #pragma unroll
    for (int off2=32; off2>0; off2>>=1) lmax = fmaxf(lmax, __shfl_down(lmax, off2));
    if (lane==0) red[wv] = lmax;
    if (ovblk){
      #pragma unroll
      for (int off2=32; off2>0; off2>>=1) omax_l = fmaxf(omax_l, __shfl_down(omax_l, off2));
      if (lane==0) redo[wv] = omax_l;
    }
    __syncthreads();

    // 1. publish this block's partials (distinct words, no RMW)
    if (tid == 0 && t < T_STEPS){
      float m = red[0];
      #pragma unroll
      for (int w2=1; w2<8; w2++) m = fmaxf(m, red[w2]);
      ASTORE(&hflag[(size_t)t*256 + blk], fmap(m));
    }
    if (tid == 0 && rid){
      float mo = redo[0];
      #pragma unroll
      for (int w2=1; w2<8; w2++) mo = fmaxf(mo, redo[w2]);
      ASTORE(&oflag[(size_t)ovt*32 + blk], fmap(mo));
    }

    // 2. leader aggregates + single-store publish
    if (blk == LEADER){
      if (t < T_STEPS && tid < 256){
        unsigned v;
        while (!(v = ALOAD(&hflag[(size_t)t*256 + tid])))
          __builtin_amdgcn_s_sleep(1);
        #pragma unroll
        for (int off2=32; off2>0; off2>>=1){
          unsigned o = (unsigned)__shfl_down((int)v, off2);
          if (o > v) v = o;
        }
        if (lane==0) sredH[wv] = v;
      }
      if (tid >= 256 && tid < 320){
        unsigned v = 0;
        if (tid < 288 && ovt >= 0 && ovt < TAIL_START){
          while (!(v = ALOAD(&oflag[(size_t)ovt*32 + (tid-256)])))
            __builtin_amdgcn_s_sleep(1);
        }
        #pragma unroll
        for (int off2=32; off2>0; off2>>=1){
          unsigned o = (unsigned)__shfl_down((int)v, off2);
          if (o > v) v = o;
        }
        if (tid == 256 && ovt >= 0 && ovt < TAIL_START)
          ASTORE(&omaxA[ovt+1], v);
      }
      __syncthreads();
      if (tid == 0 && t < T_STEPS){
        unsigned m = sredH[0];
        if (sredH[1] > m) m = sredH[1];
        if (sredH[2] > m) m = sredH[2];
        if (sredH[3] > m) m = sredH[3];
        ASTORE(&hmaxA[t+1], m);
      }
    }

    // 3. wait for publish; value is the payload
    if (!last){
      if (tid == 0){
        unsigned v;
        while (!(v = ALOAD(&hmaxA[t+1])))
          __builtin_amdgcn_s_sleep(1);
        sh_h = v;
        if (ovblk && (ovt+1) >= 0 && (ovt+1) < TAIL_START){
          unsigned v2;
          while (!(v2 = ALOAD(&omaxA[ovt+1])))
            __builtin_amdgcn_s_sleep(1);
          sh_o = v2;
        }
      }
      __syncthreads();
      hm_cur = sh_h;
      if (ovblk) om_cur = sh_o;
      g = gn;
    }
  }

  *(float4*)(hv + (size_t)gid*4) = h;
  if (ovblk){
    *(float4*)(ovs + (size_t)gid*4) = vo;
    cnt8[gid] = make_uchar4((unsigned char)(cw & 0xffu),
                            (unsigned char)((cw>>8) & 0xffu),
                            (unsigned char)((cw>>16) & 0xffu),
                            (unsigned char)((cw>>24) & 0xffu));
  }
}

// Batched GEMM2 v3: 4-way K-split. OGp[(s%RING_S)*4 + kh] = HS[s] @ Wo^T over
// K-quarter kh. gemm1-style async-LDS double buffer.
__global__ __launch_bounds__(256, 2) void gemm2_mfma(
    const _Float16* __restrict__ HS,
    const _Float16* __restrict__ WoHi, const _Float16* __restrict__ WoLo,
    float* __restrict__ OGp, int c)
{
  __shared__ __align__(16) _Float16 lds2[2][24][512];   // 48 KB
  const int tid = threadIdx.x, wave = tid>>6, lane = tid&63;
  const int bn = blockIdx.x, bm = blockIdx.y, kh = blockIdx.z;
  const int s = c*T_CHUNK + bm, ring = s % HS_RING;
  const int wm = wave>>1, wn = wave&1;
  const int kc0 = kh*32;

  const _Float16* baseA = HS   + (size_t)ring*8*128*512 + lane*8;
  const _Float16* baseH = WoHi + (size_t)bn*8*128*512 + lane*8;
  const _Float16* baseL = WoLo + (size_t)bn*8*128*512 + lane*8;

  f32x4 acc[16];
  #pragma unroll
  for (int i=0;i<16;i++) acc[i] = (f32x4){0.f,0.f,0.f,0.f};

  #pragma unroll
  for (int i=0;i<6;i++){
    int f = wave*6 + i;
    const _Float16* g = (f<8)  ? baseA + ((size_t)f*128      + kc0)*512
                     : (f<16) ? baseH + ((size_t)(f-8)*128  + kc0)*512
                              : baseL + ((size_t)(f-16)*128 + kc0)*512;
    gload_lds16(g, &lds2[0][f][0]);
  }

  for (int k=0;k<32;k++){
    __syncthreads();              // vmcnt drain + barrier: buf[k&1] ready
    if (k < 31){
      #pragma unroll
      for (int i=0;i<6;i++){
        int f = wave*6 + i;
        const _Float16* g = (f<8)  ? baseA + ((size_t)f*128      + kc0+k+1)*512
                         : (f<16) ? baseH + ((size_t)(f-8)*128  + kc0+k+1)*512
                                  : baseL + ((size_t)(f-16)*128 + kc0+k+1)*512;
        gload_lds16(g, &lds2[(k+1)&1][f][0]);
      }
    }
    const int cb = k&1;
    f16x8 fA[4], fH[4], fL[4];
    #pragma unroll
    for (int i=0;i<4;i++){
      fA[i] = *(const f16x8*)&lds2[cb][wm*4+i][lane*8];
      fH[i] = *(const f16x8*)&lds2[cb][8+wn*4+i][lane*8];
      fL[i] = *(const f16x8*)&lds2[cb][16+wn*4+i][lane*8];
    }
    #pragma unroll
    for (int i=0;i<4;i++)
      #pragma unroll
      for (int j=0;j<4;j++)
        acc[i*4+j] = __builtin_amdgcn_mfma_f32_16x16x32_f16(fA[i], fH[j], acc[i*4+j], 0,0,0);
    #pragma unroll
    for (int i=0;i<4;i++)
      #pragma unroll
      for (int j=0;j<4;j++)
        acc[i*4+j] = __builtin_amdgcn_mfma_f32_16x16x32_f16(fA[i], fL[j], acc[i*4+j], 0,0,0);
  }
  const int colw = lane&15, quad = lane>>4;
  const float sc = 1.f/256.f;
  float* eds = (float*)lds2 + wave*2048;
  __syncthreads();
  float* OGd = OGp + ((size_t)(s % RING_S)*4 + kh)*(B_DIM*O_DIM);
  #pragma unroll
  for (int ih=0; ih<2; ih++){
    #pragma unroll
    for (int il=0; il<2; il++){
      int i = ih*2+il;
      #pragma unroll
      for (int j=0;j<4;j++)
        #pragma unroll
        for (int r=0;r<4;r++)
          eds[(il*16 + quad*4 + r)*64 + j*16 + colw] = acc[i*4+j][r]*sc;
    }
    #pragma unroll
    for (int rr8=0; rr8<8; rr8++){
      int row = rr8*4 + quad;
      float4 v = *(float4*)&eds[row*64 + colw*4];
      int m = wm*64 + ih*32 + row;
      int n = bn*128 + wn*64 + colw*4;
      *(float4*)&OGd[(size_t)m*O_DIM + n] = v;
    }
  }
}

// Tail: ov steps TAIL_START..T_STEPS in ONE 16-block persistent kernel,
// with the same single-writer flag barrier (block 0 = leader).
__global__ __launch_bounds__(256) void ov_tail(
    const float* __restrict__ OGp, const float* __restrict__ ovs,
    const uchar4* __restrict__ cnt8, unsigned* __restrict__ omaxA,
    unsigned* __restrict__ oflag, float* __restrict__ out)
{
  __shared__ float red[4];
  __shared__ unsigned sh_o;
  const int tid = threadIdx.x, lane = tid&63, wv = tid>>6;
  const int f = blockIdx.x*256 + tid;
  float ov[16];
  unsigned cw[4];          // byte-packed counts per 4-group
  #pragma unroll
  for (int q=0;q<4;q++){
    int o4 = f + q*4096;
    float4 v = *(const float4*)(ovs + (size_t)o4*4);
    ov[q*4+0]=v.x; ov[q*4+1]=v.y; ov[q*4+2]=v.z; ov[q*4+3]=v.w;
    uchar4 c = cnt8[o4];
    cw[q] = (unsigned)c.x | ((unsigned)c.y<<8) | ((unsigned)c.z<<16) | ((unsigned)c.w<<24);
  }
  unsigned om_cur = omaxA[TAIL_START];    // published pre-launch (kernel boundary)

  for (int ovt = TAIL_START; ovt <= T_STEPS; ovt++){
    const float vth = vth_of(om_cur);
    const int slot = ovt % RING_S;
    float lmax = -3.0e38f;
    #pragma unroll
    for (int q=0;q<4;q++){
      int o4 = f + q*4096;
      #pragma unroll
      for (int e=0;e<4;e++){
        int idx = q*4+e;
        bool os = ov[idx] > vth;
        cw[q] += os ? (1u<<(e*8)) : 0u;
        ov[idx] = os ? 0.f : 0.5f*ov[idx];
      }
      if (ovt < T_STEPS){
        float4 g0 = *(const float4*)(OGp + ((size_t)slot*4+0)*(B_DIM*O_DIM) + (size_t)o4*4);
        float4 g1 = *(const float4*)(OGp + ((size_t)slot*4+1)*(B_DIM*O_DIM) + (size_t)o4*4);
        float4 g2 = *(const float4*)(OGp + ((size_t)slot*4+2)*(B_DIM*O_DIM) + (size_t)o4*4);
        float4 g3 = *(const float4*)(OGp + ((size_t)slot*4+3)*(B_DIM*O_DIM) + (size_t)o4*4);
        ov[q*4+0] += (g0.x+g1.x)+(g2.x+g3.x);
        ov[q*4+1] += (g0.y+g1.y)+(g2.y+g3.y);
        ov[q*4+2] += (g0.z+g1.z)+(g2.z+g3.z);
        ov[q*4+3] += (g0.w+g1.w)+(g2.w+g3.w);
        lmax = fmaxf(lmax, fmaxf(fmaxf(ov[q*4+0],ov[q*4+1]),fmaxf(ov[q*4+2],ov[q*4+3])));
      }
    }
    if (ovt == T_STEPS) break;    // last step: spike-only, no sync needed
    #pragma unroll
    for (int off=32; off>0; off>>=1) lmax = fmaxf(lmax, __shfl_down(lmax, off));
    if (lane==0) red[wv] = lmax;
    __syncthreads();
    if (tid==0){
      float m = fmaxf(fmaxf(red[0],red[1]),fmaxf(red[2],red[3]));
      ASTORE(&oflag[(size_t)ovt*32 + blockIdx.x], fmap(m));
    }
    if (blockIdx.x == 0 && tid < 64){
      unsigned v = 0;
      if (tid < 16){
        while (!(v = ALOAD(&oflag[(size_t)ovt*32 + tid])))
          __builtin_amdgcn_s_sleep(1);
      }
      #pragma unroll
      for (int off=32; off>0; off>>=1){
        unsigned o = (unsigned)__shfl_down((int)v, off);
        if (o > v) v = o;
      }
      if (tid == 0) ASTORE(&omaxA[ovt+1], v);
    }
    if (tid==0){
      unsigned v;
      while (!(v = ALOAD(&omaxA[ovt+1])))
        __builtin_amdgcn_s_sleep(1);
      sh_o = v;
    }
    __syncthreads();
    om_cur = sh_o;
  }
  #pragma unroll
  for (int q=0;q<4;q++){
    int o4 = f + q*4096;
    *(float4*)(out + (size_t)o4*4) = make_float4(
        (float)( cw[q]        & 0xffu),
        (float)((cw[q] >> 8)  & 0xffu),
        (float)((cw[q] >> 16) & 0xffu),
        (float)((cw[q] >> 24) & 0xffu));
  }
}

extern "C" void kernel_launch(void* const* d_in, const int* in_sizes, int n_in,
                              void* d_out, int out_size, void* d_ws, size_t ws_size,
                              hipStream_t stream) {
  const float* spike = (const float*)d_in[0];
  const float* Wh    = (const float*)d_in[5];   // [H, I]
  const float* Wo    = (const float*)d_in[6];   // [O, H]
  float* out = (float*)d_out;

  char* ws = (char*)d_ws;
  size_t off = 0;
  _Float16* XAhi = (_Float16*)(ws+off); off += (size_t)T_CHUNK*B_DIM*I_DIM*2;
  _Float16* XAlo = (_Float16*)(ws+off); off += (size_t)T_CHUNK*B_DIM*I_DIM*2;
  _Float16* WHhi = (_Float16*)(ws+off); off += (size_t)H_DIM*I_DIM*2;
  _Float16* WHlo = (_Float16*)(ws+off); off += (size_t)H_DIM*I_DIM*2;
  _Float16* WOhi = (_Float16*)(ws+off); off += (size_t)O_DIM*H_DIM*2;
  _Float16* WOlo = (_Float16*)(ws+off); off += (size_t)O_DIM*H_DIM*2;
  float* G  = (float*)(ws+off);         off += (size_t)T_CHUNK*B_DIM*H_DIM*4;
  float* hv = (float*)(ws+off);         off += (size_t)B_DIM*H_DIM*4;
  _Float16* HS = (_Float16*)(ws+off);   off += (size_t)HS_RING*HS_SLOT*2;
  float* OGp = (float*)(ws+off);        off += (size_t)RING_S*4*B_DIM*O_DIM*4;
  float* ovs = (float*)(ws+off);        off += (size_t)B_DIM*O_DIM*4;
  uchar4* cnt8 = (uchar4*)(ws+off);     off += (size_t)B_DIM*O_DIM;
  unsigned* hmaxA = (unsigned*)(ws+off); off += 128*4;
  unsigned* omaxA = (unsigned*)(ws+off); off += 128*4;
  unsigned* hflag = (unsigned*)(ws+off); off += (size_t)100*256*4;
  unsigned* oflag = (unsigned*)(ws+off); off += (size_t)101*32*4;
  (void)ws_size; (void)in_sizes; (void)n_in; (void)out_size;

  init_kernel<<<(B_DIM*H_DIM+255)/256, 256, 0, stream>>>(
      hv, ovs, (uint32_t*)cnt8, hmaxA, omaxA, hflag, oflag);
  prep_weights<<<288, 256, 0, stream>>>(Wh, Wo, WHhi, WHlo, WOhi, WOlo);

  for (int c = 0; c < T_STEPS/T_CHUNK; c++){
    prep_x<<<dim3(8,32,2), 256, 0, stream>>>(spike, XAhi, XAlo, c*T_CHUNK);
    gemm1_mfma<<<dim3(32, T_CHUNK), 256, 0, stream>>>(XAhi, XAlo, WHhi, WHlo, G);
    // first step of the chunk (t = 20c): emits hs_{20c-1}, needed by gemm2(c-1)
    {
      int t = c*T_CHUNK;
      int ring = (t == 0) ? (HS_RING-1) : ((t-1) % HS_RING);
      hv_step<<<528, 256, 0, stream>>>(
          G, hv, HS + (size_t)ring*HS_SLOT,
          hmaxA + t, hmaxA + t + 1, t,
          OGp, ovs, cnt8, omaxA, t - OV_LAG);
    }
    if (c > 0)
      gemm2_mfma<<<dim3(4, T_CHUNK, 4), 256, 0, stream>>>(HS, WOhi, WOlo, OGp, c-1);
    // persistent remainder of the chunk: t = 20c+1 .. 20c+19 (+ t=100 for c=4)
    {
      int nsteps = (c == T_STEPS/T_CHUNK - 1) ? T_CHUNK : (T_CHUNK - 1);
      hv_chunk<<<256, 512, 0, stream>>>(
          G + (size_t)B_DIM*H_DIM, hv, HS, hmaxA,
          OGp, ovs, cnt8, omaxA, hflag, oflag,
          c*T_CHUNK + 1, nsteps);
    }
  }
  gemm2_mfma<<<dim3(4, T_CHUNK, 4), 256, 0, stream>>>(HS, WOhi, WOlo, OGp, T_STEPS/T_CHUNK - 1);
  ov_tail<<<16, 256, 0, stream>>>(OGp, ovs, cnt8, omaxA, oflag, out);
}